// Round 8
// baseline (2454.066 us; speedup 1.0000x reference)
//
#include <hip/hip_runtime.h>

#define TSTEPS 2048
#define NB     16          // batches per block
#define NBLK   32          // 512 batches / NB
#define H1     64
#define H2     16
#define H1P    72          // padded ushort row for h1 frags (2-way banks only)
#define H2P    16

typedef short  bf16x8 __attribute__((ext_vector_type(8)));
typedef float  f32x4  __attribute__((ext_vector_type(4)));

__device__ __forceinline__ float fsig(float x) {
    return __builtin_amdgcn_rcpf(1.0f + __builtin_amdgcn_exp2f(-1.4426950408889634f * x));
}
__device__ __forceinline__ float ftanh(float x) {
    return 1.0f - 2.0f * __builtin_amdgcn_rcpf(1.0f + __builtin_amdgcn_exp2f(2.8853900817779268f * x));
}
__device__ __forceinline__ unsigned short f2bf(float f) {   // RNE f32->bf16
    unsigned u = __float_as_uint(f);
    u = (u + 0x7FFFu + ((u >> 16) & 1u)) >> 16;
    return (unsigned short)u;
}
__device__ __forceinline__ float bf2f(unsigned short h) {
    return __uint_as_float(((unsigned)h) << 16);
}
__device__ __forceinline__ f32x4 MFMA(bf16x8 a, bf16x8 b, f32x4 c) {
    return __builtin_amdgcn_mfma_f32_16x16x32_bf16(a, b, c, 0, 0, 0);
}

// 16 batches/block, 32 blocks. Waves 0-3: layer 1 (16 ch each, all 4 gates ->
// in-register cell update). Waves 4-7: layer 2, one step behind (wave 4+g owns
// gate g; cell update duplicated per wave so the h2 round-trip is wave-local).
// One barrier per phase. Weights as bf16 hi/lo MFMA fragments, pinned by
// IN-LOOP opaque asm (r6 lesson: pre-loop pins don't stop load sinking).
__global__ void __launch_bounds__(512, 1)
__attribute__((amdgpu_waves_per_eu(2, 2)))
lstm2_fused(const float* __restrict__ x,      // [512, 2048, 1]
            const float* __restrict__ w_ih1,  // [256, 1]
            const float* __restrict__ w_hh1,  // [256, 64]
            const float* __restrict__ b_ih1,  // [256]
            const float* __restrict__ b_hh1,  // [256]
            const float* __restrict__ w_ih2,  // [64, 64]
            const float* __restrict__ w_hh2,  // [64, 16]
            const float* __restrict__ b_ih2,  // [64]
            const float* __restrict__ b_hh2,  // [64]
            float* __restrict__ out)          // [512, 2048, 16]
{
    const int tid  = threadIdx.x;
    const int w    = tid >> 6;          // wave 0..7
    const int lane = tid & 63;
    const int lb   = lane & 15;         // batch column (MFMA n / C-D col)
    const int lk   = lane >> 4;         // k-group / row-group
    const size_t bglob = (size_t)blockIdx.x * NB;

    __shared__ float          x_st[2][64][NB];        // 8 KB, x chunks
    __shared__ unsigned short h1f[2][2][NB][H1P];     // [par][hi/lo][b][ch] 9 KB
    __shared__ unsigned short h2f[2][NB][H2P];        // [hi/lo][b][ch] 1 KB
    __shared__ float          g2s[2][H2][NB][4];      // activated L2 gates 8 KB
    __shared__ float          ring[32][NB][H2];       // output ring 32 KB

    // ---- init LDS: h1f parity-1 (read at p=0), h2f (h2(-1)=0), x chunk 0 ----
    for (int i = tid; i < 2 * NB * H1P; i += 512) ((unsigned short*)h1f[1])[i] = 0;
    for (int i = tid; i < 2 * NB * H2P; i += 512) ((unsigned short*)h2f)[i] = 0;
    #pragma unroll
    for (int rep = 0; rep < 2; ++rep) {
        int ii = tid + rep * 512, bb = ii >> 6, tp = ii & 63;
        x_st[0][tp][bb] = x[(bglob + bb) * TSTEPS + tp];
    }

    // ================== weight fragments (registers) ==================
    // L1 (waves 0-3): tile (gate g, ch-block w). A[m=lane&15][k=8*lk+i].
    bf16x8 a1h[4][2], a1l[4][2];
    float  wxl[4][4], bsl[4][4];
    float  c1[4] = {0.f, 0.f, 0.f, 0.f};
    // L2 (waves 4-7): gate gl = w-4; K = [h1(64) | h2(16)+pad] -> 3 chunks.
    bf16x8 a2h[3], a2l[3];
    float  bs2l[4];
    float  c2[4] = {0.f, 0.f, 0.f, 0.f};

    if (tid < 256) {
        #pragma unroll
        for (int g = 0; g < 4; ++g) {
            const float* wr = w_hh1 + (size_t)(g * H1 + 16 * w + lb) * H1;
            #pragma unroll
            for (int kc = 0; kc < 2; ++kc) {
                bf16x8 hi, lo;
                #pragma unroll
                for (int i = 0; i < 8; ++i) {
                    float f = wr[kc * 32 + lk * 8 + i];
                    unsigned short h = f2bf(f);
                    hi[i] = (short)h;
                    lo[i] = (short)f2bf(f - bf2f(h));
                }
                a1h[g][kc] = hi; a1l[g][kc] = lo;
            }
            #pragma unroll
            for (int r = 0; r < 4; ++r) {
                int row = g * H1 + 16 * w + 4 * lk + r;   // matches C/D row map
                wxl[g][r] = w_ih1[row];
                bsl[g][r] = b_ih1[row] + b_hh1[row];
            }
        }
    } else {
        const int gl = w - 4;
        const float* wr = w_ih2 + (size_t)(gl * H2 + lb) * H1;
        #pragma unroll
        for (int kc = 0; kc < 2; ++kc) {
            bf16x8 hi, lo;
            #pragma unroll
            for (int i = 0; i < 8; ++i) {
                float f = wr[kc * 32 + lk * 8 + i];
                unsigned short h = f2bf(f);
                hi[i] = (short)h;
                lo[i] = (short)f2bf(f - bf2f(h));
            }
            a2h[kc] = hi; a2l[kc] = lo;
        }
        {   // K-chunk 2: w_hh2 (k' = 8*lk+i, real for k' < 16, else zero)
            bf16x8 hi = {0,0,0,0,0,0,0,0}, lo = {0,0,0,0,0,0,0,0};
            if (lk < 2) {
                const float* wh = w_hh2 + (size_t)(gl * H2 + lb) * H2;
                #pragma unroll
                for (int i = 0; i < 8; ++i) {
                    float f = wh[lk * 8 + i];
                    unsigned short h = f2bf(f);
                    hi[i] = (short)h;
                    lo[i] = (short)f2bf(f - bf2f(h));
                }
            }
            a2h[2] = hi; a2l[2] = lo;
        }
        #pragma unroll
        for (int r = 0; r < 4; ++r) {
            int row = gl * H2 + 4 * lk + r;
            bs2l[r] = b_ih2[row] + b_hh2[row];
        }
    }
    __syncthreads();

    // ============================ main loop ============================
    // Phase p: waves 0-3 compute h1(p); waves 4-7 cell-update h2(p-2) then
    // GEMM the L2 gates for timestep p-1. One barrier.
    for (int p = 0; p < TSTEPS + 2; ++p) {
        // ---- ring flush: 16 steps, 16-step safety lag (slots disjoint) ----
        if (p >= 18 && ((p - 18) & 15) == 0) {
            int tau0 = p - 18;
            int bb = tid >> 5, sub = tid & 31;
            int tau = tau0 + (sub >> 1);
            int ch0 = (sub & 1) * 8;
            const float* src = &ring[tau & 31][bb][ch0];
            float* dst = out + ((bglob + bb) * TSTEPS + tau) * H2 + ch0;
            *(float4*)dst       = *(const float4*)src;
            *(float4*)(dst + 4) = *(const float4*)(src + 4);
        }
        // ---- x refill every 64 phases (mid-chunk, double-buffered) ----
        if ((p & 63) == 32 && p < 2016) {
            int cn = (p >> 6) + 1;
            #pragma unroll
            for (int rep = 0; rep < 2; ++rep) {
                int ii = tid + rep * 512, bb = ii >> 6, tp = ii & 63;
                x_st[cn & 1][tp][bb] = x[(bglob + bb) * TSTEPS + cn * 64 + tp];
            }
        }

        if (tid < 256) {
            // in-loop opaque pins: weights must stay register-resident
            asm volatile("" : "+v"(a1h[0][0]), "+v"(a1h[0][1]), "+v"(a1h[1][0]), "+v"(a1h[1][1]),
                              "+v"(a1h[2][0]), "+v"(a1h[2][1]), "+v"(a1h[3][0]), "+v"(a1h[3][1]));
            asm volatile("" : "+v"(a1l[0][0]), "+v"(a1l[0][1]), "+v"(a1l[1][0]), "+v"(a1l[1][1]),
                              "+v"(a1l[2][0]), "+v"(a1l[2][1]), "+v"(a1l[3][0]), "+v"(a1l[3][1]));
            if (p < TSTEPS) {
                const int wpar = p & 1, rpar = wpar ^ 1;
                const unsigned short* hb = &h1f[rpar][0][lb][lk * 8];
                const unsigned short* lp = &h1f[rpar][1][lb][lk * 8];
                bf16x8 Bh0 = *(const bf16x8*)hb;
                bf16x8 Bh1 = *(const bf16x8*)(hb + 32);
                bf16x8 Bl0 = *(const bf16x8*)lp;
                bf16x8 Bl1 = *(const bf16x8*)(lp + 32);
                f32x4 acc[4];
                #pragma unroll
                for (int g = 0; g < 4; ++g) {
                    f32x4 a = {0.f, 0.f, 0.f, 0.f};
                    a = MFMA(a1h[g][0], Bh0, a);
                    a = MFMA(a1l[g][0], Bh0, a);
                    a = MFMA(a1h[g][0], Bl0, a);
                    a = MFMA(a1h[g][1], Bh1, a);
                    a = MFMA(a1l[g][1], Bh1, a);
                    a = MFMA(a1h[g][1], Bl1, a);
                    acc[g] = a;
                }
                const float xv = x_st[(p >> 6) & 1][p & 63][lb];
                unsigned short hh[4], hl[4];
                #pragma unroll
                for (int r = 0; r < 4; ++r) {
                    float pi = acc[0][r] + wxl[0][r] * xv + bsl[0][r];
                    float pf = acc[1][r] + wxl[1][r] * xv + bsl[1][r];
                    float pg = acc[2][r] + wxl[2][r] * xv + bsl[2][r];
                    float po = acc[3][r] + wxl[3][r] * xv + bsl[3][r];
                    float gi = fsig(pi), gf = fsig(pf), gg = ftanh(pg), go = fsig(po);
                    c1[r] = gf * c1[r] + gi * gg;
                    float h = go * ftanh(c1[r]);
                    hh[r] = f2bf(h);
                    hl[r] = f2bf(h - bf2f(hh[r]));
                }
                const int ch0 = 16 * w + 4 * lk;
                *(unsigned*)&h1f[wpar][0][lb][ch0]     = (unsigned)hh[0] | ((unsigned)hh[1] << 16);
                *(unsigned*)&h1f[wpar][0][lb][ch0 + 2] = (unsigned)hh[2] | ((unsigned)hh[3] << 16);
                *(unsigned*)&h1f[wpar][1][lb][ch0]     = (unsigned)hl[0] | ((unsigned)hl[1] << 16);
                *(unsigned*)&h1f[wpar][1][lb][ch0 + 2] = (unsigned)hl[2] | ((unsigned)hl[3] << 16);
            }
        } else {
            asm volatile("" : "+v"(a2h[0]), "+v"(a2h[1]), "+v"(a2h[2]),
                              "+v"(a2l[0]), "+v"(a2l[1]), "+v"(a2l[2]));
            const int gl  = w - 4;
            const int ch0 = 4 * lk;
            // ---- duplicated L2 cell update for timestep p-2 (wave-local) ----
            if (p >= 2) {
                const int tpar = p & 1;       // (p-2)&1
                unsigned short hh[4], hl[4];
                float hs[4];
                #pragma unroll
                for (int r = 0; r < 4; ++r) {
                    f32x4 gt = *(const f32x4*)&g2s[tpar][ch0 + r][lb][0];  // i,f,g,o
                    c2[r] = gt[1] * c2[r] + gt[0] * gt[2];
                    hs[r] = gt[3] * ftanh(c2[r]);
                    hh[r] = f2bf(hs[r]);
                    hl[r] = f2bf(hs[r] - bf2f(hh[r]));
                }
                *(unsigned*)&h2f[0][lb][ch0]     = (unsigned)hh[0] | ((unsigned)hh[1] << 16);
                *(unsigned*)&h2f[0][lb][ch0 + 2] = (unsigned)hh[2] | ((unsigned)hh[3] << 16);
                *(unsigned*)&h2f[1][lb][ch0]     = (unsigned)hl[0] | ((unsigned)hl[1] << 16);
                *(unsigned*)&h2f[1][lb][ch0 + 2] = (unsigned)hl[2] | ((unsigned)hl[3] << 16);
                if (w == 4) {                  // one wave writes the ring
                    float4 v = {hs[0], hs[1], hs[2], hs[3]};
                    *(float4*)&ring[(p - 2) & 31][lb][ch0] = v;
                }
            }
            // ---- L2 GEMM for timestep p-1 (reads this phase's h2 in-wave) ----
            if (p >= 1 && p <= TSTEPS) {
                const int gp = (p - 1) & 1;
                const unsigned short* hb = &h1f[gp][0][lb][lk * 8];
                const unsigned short* lp = &h1f[gp][1][lb][lk * 8];
                bf16x8 Bh0 = *(const bf16x8*)hb;
                bf16x8 Bh1 = *(const bf16x8*)(hb + 32);
                bf16x8 Bl0 = *(const bf16x8*)lp;
                bf16x8 Bl1 = *(const bf16x8*)(lp + 32);
                bf16x8 B2h = {0,0,0,0,0,0,0,0}, B2l = {0,0,0,0,0,0,0,0};
                if (lk < 2) {
                    B2h = *(const bf16x8*)&h2f[0][lb][lk * 8];
                    B2l = *(const bf16x8*)&h2f[1][lb][lk * 8];
                }
                f32x4 a = {0.f, 0.f, 0.f, 0.f};
                a = MFMA(a2h[0], Bh0, a);
                a = MFMA(a2l[0], Bh0, a);
                a = MFMA(a2h[0], Bl0, a);
                a = MFMA(a2h[1], Bh1, a);
                a = MFMA(a2l[1], Bh1, a);
                a = MFMA(a2h[1], Bl1, a);
                a = MFMA(a2h[2], B2h, a);
                a = MFMA(a2l[2], B2h, a);
                a = MFMA(a2h[2], B2l, a);
                #pragma unroll
                for (int r = 0; r < 4; ++r) {
                    float pre = a[r] + bs2l[r];
                    float av = (gl == 2) ? ftanh(pre) : fsig(pre);
                    g2s[gp][ch0 + r][lb][gl] = av;     // [ch][b][gate]
                }
            }
        }
        __syncthreads();
    }

    // ---- tail flush: timesteps 2032..2047 ----
    {
        int bb = tid >> 5, sub = tid & 31;
        int tau = 2032 + (sub >> 1);
        int ch0 = (sub & 1) * 8;
        const float* src = &ring[tau & 31][bb][ch0];
        float* dst = out + ((bglob + bb) * TSTEPS + tau) * H2 + ch0;
        *(float4*)dst       = *(const float4*)src;
        *(float4*)(dst + 4) = *(const float4*)(src + 4);
    }
}

extern "C" void kernel_launch(void* const* d_in, const int* in_sizes, int n_in,
                              void* d_out, int out_size, void* d_ws, size_t ws_size,
                              hipStream_t stream) {
    const float* x     = (const float*)d_in[0];
    const float* w_ih1 = (const float*)d_in[1];
    const float* w_hh1 = (const float*)d_in[2];
    const float* b_ih1 = (const float*)d_in[3];
    const float* b_hh1 = (const float*)d_in[4];
    const float* w_ih2 = (const float*)d_in[5];
    const float* w_hh2 = (const float*)d_in[6];
    const float* b_ih2 = (const float*)d_in[7];
    const float* b_hh2 = (const float*)d_in[8];
    float* out = (float*)d_out;

    lstm2_fused<<<NBLK, 512, 0, stream>>>(x, w_ih1, w_hh1, b_ih1, b_hh1,
                                          w_ih2, w_hh2, b_ih2, b_hh2, out);
}

// Round 9
// 1234.449 us; speedup vs baseline: 1.9880x; 1.9880x over previous
//
#include <hip/hip_runtime.h>

#define TSTEPS 2048
#define NBATCH 512
#define H1 64
#define H2 16

typedef _Float16 h2v __attribute__((ext_vector_type(2)));

__device__ __forceinline__ float fsig(float x) {
    return __builtin_amdgcn_rcpf(1.0f + __builtin_amdgcn_exp2f(-1.4426950408889634f * x));
}
__device__ __forceinline__ float ftanh(float x) {
    // tanh(x) = 1 - 2/(exp2(2x*log2e)+1); saturates correctly at +-inf
    return 1.0f - 2.0f * __builtin_amdgcn_rcpf(1.0f + __builtin_amdgcn_exp2f(2.8853900817779268f * x));
}
// branchless: k2==1 -> sigmoid(x); k2==2 -> tanh(x) = 2*sig(2x)-1
__device__ __forceinline__ float act(float x, float k2) {
    return k2 * fsig(k2 * x) - (k2 - 1.0f);
}

#if __has_builtin(__builtin_amdgcn_fdot2)
__device__ __forceinline__ float dot2(int wp, int hp, float acc) {
    return __builtin_amdgcn_fdot2(__builtin_bit_cast(h2v, wp),
                                  __builtin_bit_cast(h2v, hp), acc, false);
}
#else
__device__ __forceinline__ float dot2(int wp, int hp, float acc) {
    h2v a = __builtin_bit_cast(h2v, wp), b = __builtin_bit_cast(h2v, hp);
    return acc + (float)a.x * (float)b.x + (float)a.y * (float)b.y;
}
#endif

__device__ __forceinline__ int packh2(float a, float b) {
    h2v v; v.x = (_Float16)a; v.y = (_Float16)b;
    return __builtin_bit_cast(int, v);
}
template<int CTRL>
__device__ __forceinline__ float dpp_bcast(float v) {   // quad broadcast
    int r = __builtin_amdgcn_mov_dpp(__float_as_int(v), CTRL, 0xF, 0xF, true);
    return __int_as_float(r);
}

// ONE WAVE PER BATCH, ZERO BARRIERS (r8 post-mortem: every barrier-coupled
// design stalls at 2100-2700 cyc/step; sync + per-wave h-broadcast cost).
// Lane j owns all 4 gates of L1 channel j (full k=64) -> in-lane cell update.
// L2 runs one step behind in the same wave, reusing this phase's h1 registers;
// its 4-gate gather is an intra-quad DPP broadcast. Weights live in VGPRs as
// packed f16 pairs, consumed by v_dot2_f32_f16 (f32 accumulate).
__global__ void __launch_bounds__(64, 1)
__attribute__((amdgpu_waves_per_eu(1, 1)))
lstm2_fused(const float* __restrict__ x,      // [512, 2048, 1]
            const float* __restrict__ w_ih1,  // [256, 1]
            const float* __restrict__ w_hh1,  // [256, 64]
            const float* __restrict__ b_ih1,  // [256]
            const float* __restrict__ b_hh1,  // [256]
            const float* __restrict__ w_ih2,  // [64, 64]
            const float* __restrict__ w_hh2,  // [64, 16]
            const float* __restrict__ b_ih2,  // [64]
            const float* __restrict__ b_hh2,  // [64]
            float* __restrict__ out)          // [512, 2048, 16]
{
    const int lane = threadIdx.x;     // 64 threads = 1 wave
    const int b    = blockIdx.x;      // 1 batch per block

    __shared__ float    x_lds[TSTEPS];     // 8 KB
    __shared__ _Float16 h1_lds[H1];        // 128 B
    __shared__ _Float16 h2_lds[H2];        // 32 B
    __shared__ float    ring[32][H2];      // 2 KB output ring

    // ---- stage x[b,:] ----
    {
        const float4* xs = (const float4*)(x + (size_t)b * TSTEPS);
        float4* xd = (float4*)x_lds;
        #pragma unroll
        for (int i = 0; i < 8; ++i) xd[lane + 64 * i] = xs[lane + 64 * i];
    }
    if (lane < 32) ((int*)h1_lds)[lane] = 0;
    if (lane < 8)  ((int*)h2_lds)[lane] = 0;

    // ---- L1 weights: lane j; gate rows {j, 64+j, 128+j, 192+j}, k=0..63 ----
    int   w1[4][32];                   // packed f16 pairs
    float wx1[4], bs1[4];
    #pragma unroll
    for (int g = 0; g < 4; ++g) {
        const int r = g * H1 + lane;
        const float* wr = w_hh1 + (size_t)r * H1;
        #pragma unroll
        for (int k = 0; k < 32; ++k) w1[g][k] = packh2(wr[2 * k], wr[2 * k + 1]);
        wx1[g] = w_ih1[r];
        bs1[g] = b_ih1[r] + b_hh1[r];
    }
    // ---- L2 weights: lane -> channel m = lane>>2, gate g2 = lane&3 ----
    const int m  = lane >> 2;
    const int g2 = lane & 3;
    const int r2 = g2 * H2 + m;
    int w2[32], wh2[8];
    #pragma unroll
    for (int k = 0; k < 32; ++k)
        w2[k] = packh2(w_ih2[(size_t)r2 * H1 + 2 * k], w_ih2[(size_t)r2 * H1 + 2 * k + 1]);
    #pragma unroll
    for (int k = 0; k < 8; ++k)
        wh2[k] = packh2(w_hh2[(size_t)r2 * H2 + 2 * k], w_hh2[(size_t)r2 * H2 + 2 * k + 1]);
    const float bs2 = b_ih2[r2] + b_hh2[r2];
    const float k22 = (g2 == 2) ? 2.0f : 1.0f;

    float c1 = 0.0f;                  // cell of channel j (lane-private)
    float c2 = 0.0f;                  // cell of channel m (replicated per quad)
    float* outb = out + (size_t)b * TSTEPS * H2;

    for (int p = 0; p <= TSTEPS; ++p) {
        // in-loop opaque pins: keep weights register-resident (r6/r8 lesson)
        #pragma unroll
        for (int g = 0; g < 4; ++g)
            #pragma unroll
            for (int k = 0; k < 32; ++k) asm volatile("" : "+v"(w1[g][k]));
        #pragma unroll
        for (int k = 0; k < 32; ++k) asm volatile("" : "+v"(w2[k]));
        #pragma unroll
        for (int k = 0; k < 8; ++k)  asm volatile("" : "+v"(wh2[k]));

        // ---- output flush: every 16 steps, slots written 16-31 steps ago ----
        const int tau_f = p - 1;
        if (tau_f >= 31 && (tau_f & 15) == 15) {
            const int tau0 = (tau_f & ~15) - 16;
            const int tt = tau0 + (lane >> 2), ch0 = (lane & 3) * 4;
            float4 v = *(const float4*)&ring[tt & 31][ch0];
            *(float4*)(outb + (size_t)tt * H2 + ch0) = v;      // 1 KB coalesced
        }

        // ---- broadcast-read h1(p-1) once; reused by L1(p) and L2(p-1) ----
        int hp[32];
        {
            const int4* hs = (const int4*)h1_lds;
            #pragma unroll
            for (int i = 0; i < 8; ++i) {
                int4 v = hs[i];
                hp[4*i+0] = v.x; hp[4*i+1] = v.y; hp[4*i+2] = v.z; hp[4*i+3] = v.w;
            }
        }

        // ===== Layer 1, timestep p =====
        if (p < TSTEPS) {
            const float xv = x_lds[p];
            float ai = bs1[0] + wx1[0] * xv;
            float af = bs1[1] + wx1[1] * xv;
            float ag = bs1[2] + wx1[2] * xv;
            float ao = bs1[3] + wx1[3] * xv;
            #pragma unroll
            for (int k = 0; k < 32; ++k) {      // 4 independent dot2 chains
                ai = dot2(w1[0][k], hp[k], ai);
                af = dot2(w1[1][k], hp[k], af);
                ag = dot2(w1[2][k], hp[k], ag);
                ao = dot2(w1[3][k], hp[k], ao);
            }
            float gi = fsig(ai), gf = fsig(af), gg = ftanh(ag), go = fsig(ao);
            c1 = gf * c1 + gi * gg;
            float h1n = go * ftanh(c1);
            h1_lds[lane] = (_Float16)h1n;       // ds_write_b16; same-wave FIFO
        }

        // ===== Layer 2, timestep p-1 (same wave, no sync) =====
        if (p >= 1) {
            int hq[8];
            {
                const int4* hs = (const int4*)h2_lds;   // h2(p-2)
                int4 u0 = hs[0], u1 = hs[1];
                hq[0]=u0.x; hq[1]=u0.y; hq[2]=u0.z; hq[3]=u0.w;
                hq[4]=u1.x; hq[5]=u1.y; hq[6]=u1.z; hq[7]=u1.w;
            }
            float a0 = bs2, a1 = 0.f, a2a = 0.f, a3 = 0.f;
            #pragma unroll
            for (int k = 0; k < 8; ++k) {       // 4 chains over w_ih2
                a0  = dot2(w2[4*k+0], hp[4*k+0], a0);
                a1  = dot2(w2[4*k+1], hp[4*k+1], a1);
                a2a = dot2(w2[4*k+2], hp[4*k+2], a2a);
                a3  = dot2(w2[4*k+3], hp[4*k+3], a3);
            }
            #pragma unroll
            for (int k = 0; k < 2; ++k) {       // w_hh2 (16 k)
                a0  = dot2(wh2[4*k+0], hq[4*k+0], a0);
                a1  = dot2(wh2[4*k+1], hq[4*k+1], a1);
                a2a = dot2(wh2[4*k+2], hq[4*k+2], a2a);
                a3  = dot2(wh2[4*k+3], hq[4*k+3], a3);
            }
            float av = act((a0 + a1) + (a2a + a3), k22);
            // gather the quad's 4 gates (i,f,g,o) via DPP broadcast
            float gi = dpp_bcast<0x00>(av);
            float gf = dpp_bcast<0x55>(av);
            float gg = dpp_bcast<0xAA>(av);
            float go = dpp_bcast<0xFF>(av);
            c2 = gf * c2 + gi * gg;
            float h2n = go * ftanh(c2);
            if (g2 == 0) {
                h2_lds[m] = (_Float16)h2n;
                ring[(p - 1) & 31][m] = h2n;
            }
        }
    }

    // ---- tail flush: timesteps 2032..2047 ----
    {
        const int tt = 2032 + (lane >> 2), ch0 = (lane & 3) * 4;
        float4 v = *(const float4*)&ring[tt & 31][ch0];
        *(float4*)(outb + (size_t)tt * H2 + ch0) = v;
    }
}

extern "C" void kernel_launch(void* const* d_in, const int* in_sizes, int n_in,
                              void* d_out, int out_size, void* d_ws, size_t ws_size,
                              hipStream_t stream) {
    const float* x     = (const float*)d_in[0];
    const float* w_ih1 = (const float*)d_in[1];
    const float* w_hh1 = (const float*)d_in[2];
    const float* b_ih1 = (const float*)d_in[3];
    const float* b_hh1 = (const float*)d_in[4];
    const float* w_ih2 = (const float*)d_in[5];
    const float* w_hh2 = (const float*)d_in[6];
    const float* b_ih2 = (const float*)d_in[7];
    const float* b_hh2 = (const float*)d_in[8];
    float* out = (float*)d_out;

    lstm2_fused<<<NBATCH, 64, 0, stream>>>(x, w_ih1, w_hh1, b_ih1, b_hh1,
                                           w_ih2, w_hh2, b_ih2, b_hh2, out);
}